// Round 1
// baseline (425.621 us; speedup 1.0000x reference)
//
#include <hip/hip_runtime.h>
#include <cstdint>
#include <cstddef>

typedef float v4f __attribute__((ext_vector_type(4)));
typedef short short8 __attribute__((ext_vector_type(8)));

constexpr int B_ = 8, P_ = 16384, Q_ = 256, E_ = 128;

// ---------- helpers ----------
__device__ __forceinline__ unsigned short f2bf(float f) {
  unsigned int x = __float_as_uint(f);
  x += 0x7FFFu + ((x >> 16) & 1u);           // round-to-nearest-even
  return (unsigned short)(x >> 16);
}
__device__ __forceinline__ float softplus_f(float x) {
  return fmaxf(x, 0.f) + __logf(1.f + __expf(-fabsf(x)));
}

// ---------- P1: per-(b,p) row pass over mask_logit_values ----------
// writes A1 = (m ? -x : 0) and pred_p = softmax_q(masked x) as bf16 [B,P,Q],
// accumulates negsum[b,q] = sum_p softplus(x)*m and ppsum[b,q] = sum_p pred_p.
__global__ __launch_bounds__(256) void prep_rows(
    const float* __restrict__ mlv, const int* __restrict__ mask,
    unsigned short* __restrict__ A1, unsigned short* __restrict__ PP,
    float* __restrict__ negsum, float* __restrict__ ppsum)
{
  __shared__ float rn[4][256];
  __shared__ float rp[4][256];
  const int t = threadIdx.x, w = t >> 6, l = t & 63;
  const int b = blockIdx.x >> 7;                  // 128 blocks per image
  float accN[4] = {0,0,0,0}, accP[4] = {0,0,0,0};
  for (int it = 0; it < 32; ++it) {
    const size_t row = (size_t)blockIdx.x * 128 + it * 4 + w;
    const size_t off = row * 256 + l * 4;
    float4 x4 = *(const float4*)(mlv + off);
    int4   m4 = *(const int4*)(mask + off);
    float xs[4] = {x4.x, x4.y, x4.z, x4.w};
    int   ms[4] = {m4.x, m4.y, m4.z, m4.w};
    float ez[4]; float s = 0.f;
    unsigned short a1u[4];
#pragma unroll
    for (int j = 0; j < 4; ++j) {
      bool m = (ms[j] != 0);
      float x = xs[j];
      float e = m ? __expf(x) : 0.f;              // no max-subtraction needed: |x| small
      ez[j] = e; s += e;
      a1u[j] = f2bf(m ? -x : 0.f);
      accN[j] += m ? softplus_f(x) : 0.f;
    }
#pragma unroll
    for (int o = 32; o > 0; o >>= 1) s += __shfl_xor(s, o, 64);
    float inv = (s > 0.f) ? (1.f / s) : 0.f;
    unsigned short pu[4];
#pragma unroll
    for (int j = 0; j < 4; ++j) { float p = ez[j] * inv; accP[j] += p; pu[j] = f2bf(p); }
    uint2 aw, pw;
    aw.x = (unsigned)a1u[0] | ((unsigned)a1u[1] << 16);
    aw.y = (unsigned)a1u[2] | ((unsigned)a1u[3] << 16);
    pw.x = (unsigned)pu[0] | ((unsigned)pu[1] << 16);
    pw.y = (unsigned)pu[2] | ((unsigned)pu[3] << 16);
    *(uint2*)(A1 + off) = aw;
    *(uint2*)(PP + off) = pw;
  }
#pragma unroll
  for (int j = 0; j < 4; ++j) { rn[w][l * 4 + j] = accN[j]; rp[w][l * 4 + j] = accP[j]; }
  __syncthreads();
  float sn = rn[0][t] + rn[1][t] + rn[2][t] + rn[3][t];
  float sq = rp[0][t] + rp[1][t] + rp[2][t] + rp[3][t];
  atomicAdd(&negsum[b * 256 + t], sn);
  atomicAdd(&ppsum[b * 256 + t], sq);
}

// ---------- P2: segmap -> bf16 + column sums + nnz ----------
__global__ __launch_bounds__(256) void prep_seg(
    const float* __restrict__ seg, unsigned short* __restrict__ SG,
    float* __restrict__ segsum, float* __restrict__ nnzb)
{
  __shared__ float sbin[128];
  __shared__ float nns;
  const int t = threadIdx.x;
  const int b = blockIdx.x >> 6;                  // 64 blocks per image
  if (t < 128) sbin[t] = 0.f;
  if (t == 0) nns = 0.f;
  __syncthreads();
  float accS[4] = {0,0,0,0}; float cnt = 0.f;
  const size_t base = (size_t)blockIdx.x * 32768 + t * 4;
  for (int it = 0; it < 32; ++it) {
    size_t off = base + (size_t)it * 1024;
    float4 v = *(const float4*)(seg + off);
    float vs[4] = {v.x, v.y, v.z, v.w};
    unsigned short u[4];
#pragma unroll
    for (int j = 0; j < 4; ++j) {
      u[j] = f2bf(vs[j]); accS[j] += vs[j];
      cnt += (vs[j] > 0.f) ? 1.f : 0.f;
    }
    uint2 wv; wv.x = (unsigned)u[0] | ((unsigned)u[1] << 16);
    wv.y = (unsigned)u[2] | ((unsigned)u[3] << 16);
    *(uint2*)(SG + off) = wv;
  }
  const int e0 = (t * 4) & 127;
#pragma unroll
  for (int j = 0; j < 4; ++j) atomicAdd(&sbin[e0 + j], accS[j]);
#pragma unroll
  for (int o = 32; o > 0; o >>= 1) cnt += __shfl_xor(cnt, o, 64);
  if ((t & 63) == 0) atomicAdd(&nns, cnt);
  __syncthreads();
  if (t < 128) atomicAdd(&segsum[b * 128 + t], sbin[t]);
  if (t == 0) atomicAdd(&nnzb[b], nns);
}

// ---------- GEMM: split-K bf16 MFMA, C[q,e] = sum_p A[p,q]*Bm[p,e] ----------
// grid = B * 2(qtile) * 2(gemm) * 16(ksplit) = 512 blocks, 256 threads.
// gemm 0: A=A1, Bm=binarize(SG); gemm 1: A=PP, Bm=SG.
// Transpose-through-LDS: tiles stored [col][k] with 144 B rows (64 bf16 + pad).
__global__ __launch_bounds__(256) void gemm_split(
    const unsigned short* __restrict__ A1, const unsigned short* __restrict__ PP,
    const unsigned short* __restrict__ SG, float* __restrict__ part)
{
  __shared__ __align__(16) unsigned int ldsA[128 * 36];
  __shared__ __align__(16) unsigned int ldsB[128 * 36];
  const int id = blockIdx.x;
  const int ks = id & 15, qt = (id >> 4) & 1, g = (id >> 5) & 1, b = id >> 6;
  const unsigned short* Aop = (g ? PP : A1) + (size_t)b * P_ * Q_;
  const unsigned short* Bop = SG + (size_t)b * P_ * E_;
  const int t = threadIdx.x;
  const int c16 = t >> 4, pr = t & 15;
  const int w = t >> 6, l = t & 63, lm = l & 15, quad = l >> 4;
  const int wm = w & 1, wn = w >> 1;
  v4f acc[4][4];
#pragma unroll
  for (int i = 0; i < 4; ++i)
#pragma unroll
    for (int j = 0; j < 4; ++j) acc[i][j] = (v4f)0.f;

  for (int c = 0; c < 16; ++c) {
    const int pbase = ks * 1024 + c * 64;
    __syncthreads();
#pragma unroll
    for (int pass = 0; pass < 2; ++pass) {
      const int r0 = pass * 32 + 2 * pr;
      const unsigned short* ap = Aop + (size_t)(pbase + r0) * Q_ + qt * 128 + c16 * 8;
      uint4 w0 = *(const uint4*)ap;
      uint4 w1 = *(const uint4*)(ap + Q_);
      const unsigned short* bp = Bop + (size_t)(pbase + r0) * E_ + c16 * 8;
      uint4 v0 = *(const uint4*)bp;
      uint4 v1 = *(const uint4*)(bp + E_);
      const int dbase = pass * 16 + pr;
      unsigned int aw0[4] = {w0.x, w0.y, w0.z, w0.w};
      unsigned int aw1[4] = {w1.x, w1.y, w1.z, w1.w};
      unsigned int bw0[4] = {v0.x, v0.y, v0.z, v0.w};
      unsigned int bw1[4] = {v1.x, v1.y, v1.z, v1.w};
#pragma unroll
      for (int k = 0; k < 4; ++k) {
        const int col = c16 * 8 + 2 * k;
        unsigned int lo = (aw0[k] & 0xFFFFu) | (aw1[k] << 16);
        unsigned int hi = (aw0[k] >> 16) | (aw1[k] & 0xFFFF0000u);
        ldsA[col * 36 + dbase] = lo;
        ldsA[(col + 1) * 36 + dbase] = hi;
        unsigned int blo = (bw0[k] & 0xFFFFu) | (bw1[k] << 16);
        unsigned int bhi = (bw0[k] >> 16) | (bw1[k] & 0xFFFF0000u);
        if (g == 0) {  // binarized target: nonzero -> bf16 1.0
          blo = ((blo & 0xFFFFu) ? 0x3F80u : 0u) | ((blo & 0xFFFF0000u) ? 0x3F800000u : 0u);
          bhi = ((bhi & 0xFFFFu) ? 0x3F80u : 0u) | ((bhi & 0xFFFF0000u) ? 0x3F800000u : 0u);
        }
        ldsB[col * 36 + dbase] = blo;
        ldsB[(col + 1) * 36 + dbase] = bhi;
      }
    }
    __syncthreads();
#pragma unroll
    for (int k32 = 0; k32 < 2; ++k32) {
      short8 af[4], bf[4];
#pragma unroll
      for (int i = 0; i < 4; ++i) {
        const int arow = wm * 64 + i * 16 + lm;
        af[i] = *(const short8*)((const char*)ldsA + arow * 144 + k32 * 64 + quad * 16);
        const int brow = wn * 64 + i * 16 + lm;
        bf[i] = *(const short8*)((const char*)ldsB + brow * 144 + k32 * 64 + quad * 16);
      }
#pragma unroll
      for (int i = 0; i < 4; ++i)
#pragma unroll
        for (int j = 0; j < 4; ++j)
          acc[i][j] = __builtin_amdgcn_mfma_f32_16x16x32_bf16(af[i], bf[j], acc[i][j], 0, 0, 0);
    }
  }
  float* pout = part + ((size_t)(g * 8 + b) * 16 + ks) * (Q_ * E_);
#pragma unroll
  for (int i = 0; i < 4; ++i)
#pragma unroll
    for (int r = 0; r < 4; ++r) {
      const int q = qt * 128 + wm * 64 + i * 16 + quad * 4 + r;
#pragma unroll
      for (int j = 0; j < 4; ++j) {
        const int e = wn * 64 + j * 16 + lm;
        pout[q * E_ + e] = acc[i][j][r];
      }
    }
}

// ---------- epilogue: reduce K-slices + all cost terms ----------
__global__ __launch_bounds__(128) void epilogue(
    const float* __restrict__ part,
    const float* __restrict__ negsum, const float* __restrict__ ppsum,
    const float* __restrict__ segsum, const float* __restrict__ nnzb,
    const float* __restrict__ logits, const float* __restrict__ ppos,
    const float* __restrict__ chol, const float* __restrict__ tpos,
    const float* __restrict__ imgsz, float* __restrict__ out)
{
  const int bq = blockIdx.x;          // b*256 + q
  const int b = bq >> 8;
  const int e = threadIdx.x;
  const int qe = (bq & 255) * 128 + e;
  const float* p0 = part + (size_t)b * 524288 + qe;
  const float* p1 = part + (size_t)(8 + b) * 524288 + qe;
  float g1 = 0.f, g2 = 0.f;
#pragma unroll
  for (int k = 0; k < 16; ++k) { g1 += p0[k * 32768]; g2 += p1[k * 32768]; }

  const float nnz = fmaxf(nnzb[b], 1.f);
  const float mask_cost = (negsum[bq] + g1) / nnz;
  const float dice = 1.f - (2.f * g2 + 1.f) / (ppsum[bq] + segsum[b * 128 + e] + 1.f);
  const float cls = softplus_f(-logits[bq]);
  const float px = ppos[bq * 2], py = ppos[bq * 2 + 1];
  const float tx = tpos[(b * 128 + e) * 2], ty = tpos[(b * 128 + e) * 2 + 1];
  const float dx = px - tx, dy = py - ty;
  const float ax = fabsf(dx), ay = fabsf(dy);
  const float hx = (ax < 1.f) ? 0.5f * dx * dx : ax - 0.5f;
  const float hy = (ay < 1.f) ? 0.5f * dy * dy : ay - 0.5f;
  const float huber = 0.5f * (hx + hy);
  const float sx = imgsz[b * 2], sy = imgsz[b * 2 + 1];
  const float L00 = chol[bq * 4 + 0], L10 = chol[bq * 4 + 2], L11 = chol[bq * 4 + 3];
  const float d0 = (tx - px) * sx, d1 = (ty - py) * sy;
  const float z0 = d0 / L00;
  const float z1 = (d1 - L10 * z0) / L11;
  const float nll = 0.5f * (z0 * z0 + z1 * z1) + 1.8378770664093453f + __logf(L00) + __logf(L11);
  const float lik = 1.f - __expf(-nll);
  out[bq * 128 + e] = 2.f * cls + 5.f * mask_cost + 5.f * dice + huber + 0.5f * nll + 0.5f * lik;
}

// ---------- launcher ----------
extern "C" void kernel_launch(void* const* d_in, const int* in_sizes, int n_in,
                              void* d_out, int out_size, void* d_ws, size_t ws_size,
                              hipStream_t stream)
{
  (void)in_sizes; (void)n_in; (void)out_size; (void)ws_size;
  const float* logits = (const float*)d_in[0];
  const float* mlv    = (const float*)d_in[1];
  const int*   mask   = (const int*)d_in[2];
  const float* seg    = (const float*)d_in[3];
  const float* ppos   = (const float*)d_in[4];
  const float* chol   = (const float*)d_in[5];
  const float* tpos   = (const float*)d_in[6];
  const float* imgsz  = (const float*)d_in[7];

  char* ws = (char*)d_ws;
  unsigned short* A1 = (unsigned short*)(ws);              //  67108864 B
  unsigned short* PP = (unsigned short*)(ws + 67108864);   //  67108864 B
  unsigned short* SG = (unsigned short*)(ws + 134217728);  //  33554432 B
  float* part   = (float*)(ws + 167772160);                //  67108864 B
  float* negsum = (float*)(ws + 234881024);                //  8192 B
  float* ppsum  = (float*)(ws + 234889216);                //  8192 B
  float* segsum = (float*)(ws + 234897408);                //  4096 B
  float* nnzb   = (float*)(ws + 234901504);                //  32 B

  hipMemsetAsync(ws + 234881024, 0, 20544, stream);
  prep_rows<<<1024, 256, 0, stream>>>(mlv, mask, A1, PP, negsum, ppsum);
  prep_seg<<<512, 256, 0, stream>>>(seg, SG, segsum, nnzb);
  gemm_split<<<512, 256, 0, stream>>>(A1, PP, SG, part);
  epilogue<<<2048, 128, 0, stream>>>(part, negsum, ppsum, segsum, nnzb,
                                     logits, ppos, chol, tpos, imgsz, (float*)d_out);
}